// Round 11
// baseline (249.662 us; speedup 1.0000x reference)
//
#include <hip/hip_runtime.h>

#define IN_F   128
#define OUTD   64
#define HOUT   256      // H*OUT
#define NEG_SLOPE 0.2f
#define BN_EPS 1e-5f
#define HISTB  512      // dedicated histogram blocks — FIRST in blockIdx order

typedef __attribute__((ext_vector_type(8))) short bf16x8;
typedef __attribute__((ext_vector_type(4))) float f32x4;
typedef __attribute__((ext_vector_type(2))) float f32x2;

__device__ __forceinline__ unsigned short f2bf(float f) {
    union { float f; unsigned u; } v; v.f = f;
    unsigned r = (v.u + 0x7FFF + ((v.u >> 16) & 1)) >> 16;   // RNE
    return (unsigned short)r;
}
__device__ __forceinline__ float bf2f(unsigned short h) {
    union { unsigned u; float f; } v; v.u = ((unsigned)h) << 16;
    return v.f;
}

// fragment-order index for Btg2. Tiles (tt=0..9), j=0..3, ks=0..3, 16 cols (n15), 8 k (kk).
//  tt 0..3 (Hh,  s=tt):   col = j*64 + tt*16 + n15          (j = head)
//  tt 4..7 (Hr,  s=tt-4): col = 256 + j*64 + (tt-4)*16 + n15 (j = head)
//  tt 8    (Rres):        col = 512 + j*16 + n15
//  tt 9    (el/er):       col = 576 + n15, j=0 only
__device__ __forceinline__ int b2idx(int c, int k) {
    int tt, j;
    if (c < 256)      { tt = (c >> 4) & 3;                     j = c >> 6; }
    else if (c < 512) { int cc = c - 256; tt = 4 + ((cc >> 4) & 3); j = cc >> 6; }
    else if (c < 576) { int cc = c - 512; tt = 8;              j = cc >> 4; }
    else              { tt = 9;                                j = 0; }
    int n15 = c & 15;
    int ks = k >> 5, qd = (k >> 3) & 3, kk = k & 7;
    return ((((tt * 4 + j) * 4 + ks) * 64) + qd * 16 + n15) * 8 + kk;
}

// ============ K0: pack weights -> Btg2 (fragment-ordered bf16) ============
__global__ __launch_bounds__(256) void k0_pack(
    const float* __restrict__ W_fc, const float* __restrict__ W_gres,
    const float* __restrict__ W_res,
    const float* __restrict__ attn_l, const float* __restrict__ attn_r,
    unsigned short* __restrict__ Btg2)
{
    int bid = blockIdx.x, t = threadIdx.x;
    if (bid < 288) {
        int idx = bid * 256 + t;          // c*128 + k, c < 576
        int c = idx >> 7, k = idx & 127;
        float v;
        if (c < 256)      v = W_fc[k * HOUT + c];
        else if (c < 512) v = W_gres[k * HOUT + (c - 256)];
        else              v = W_res[k * OUTD + (c - 512)];
        Btg2[b2idx(c, k)] = f2bf(v);
        return;
    }
    // bid == 288: wl/wr folded attention vectors (cols 576..583); 584..591 zero
    for (int p = t; p < 512; p += 256) {
        int h = p >> 7, k = p & 127;
        float sl = 0.f, sr = 0.f;
        for (int d = 0; d < 64; ++d) {
            float wv = W_fc[k * HOUT + h * 64 + d];
            sl += wv * attn_l[h * 64 + d];
            sr += wv * attn_r[h * 64 + d];
        }
        Btg2[b2idx(576 + h, k)] = f2bf(sl);
        Btg2[b2idx(580 + h, k)] = f2bf(sr);
    }
    for (int p = t; p < 8 * 128; p += 256) {
        int c = 584 + (p >> 7), k = p & 127;
        Btg2[b2idx(c, k)] = 0;
    }
}

// ============ K1: hist blocks FIRST (overlap from t=0), then GEMM blocks ============
__global__ __launch_bounds__(256) void k1_gemm(
    const float* __restrict__ A, const unsigned short* __restrict__ Btg2,
    const float* __restrict__ gat_bias, const float* __restrict__ res_b,
    const int* __restrict__ dst, int* __restrict__ degree, int* __restrict__ rank,
    unsigned char* __restrict__ Hh8, unsigned char* __restrict__ Hr8,
    unsigned short* __restrict__ Rres,
    float* __restrict__ el, float* __restrict__ er,
    int N, int E)
{
    int t = threadIdx.x;

    if (blockIdx.x < HISTB) {
        // ---- histogram role: starts at t=0, concurrent with GEMM blocks ----
        int ht = blockIdx.x * 256 + t;
        for (int e = ht; e < E; e += HISTB * 256)
            rank[e] = atomicAdd(degree + dst[e], 1);
        return;
    }

    int w = t >> 6, lane = t & 63, quad = lane >> 4, n15 = lane & 15;
    int gw = (blockIdx.x - HISTB) * 4 + w;
    int T = (N + 15) / 16;
    if (gw >= T) return;

    int m0 = gw * 16;
    bool full = (m0 + 16 <= N);
    int lofs = (quad * 16 + n15) * 8;     // lane slot within a 1KB fragment block

    // A fragments: 4 ks, fp32 -> bf16 in-register (row = m0 + n15)
    bf16x8 af[4];
    {
        int r = m0 + n15;
#pragma unroll
        for (int ks = 0; ks < 4; ++ks) {
            float4 v0 = make_float4(0.f, 0.f, 0.f, 0.f), v1 = v0;
            if (r < N) {
                const float* ap = A + (size_t)r * IN_F + ks * 32 + quad * 8;
                v0 = *(const float4*)ap;
                v1 = *(const float4*)(ap + 4);
            }
            bf16x8 o;
            o[0] = f2bf(v0.x); o[1] = f2bf(v0.y); o[2] = f2bf(v0.z); o[3] = f2bf(v0.w);
            o[4] = f2bf(v1.x); o[5] = f2bf(v1.y); o[6] = f2bf(v1.z); o[7] = f2bf(v1.w);
            af[ks] = o;
        }
    }

    // ---- Hh: tiles 0..3 (j = head) -> transient dword pack+store ----
#pragma unroll
    for (int s = 0; s < 4; ++s) {
        f32x4 acc[4] = {};
#pragma unroll
        for (int ks = 0; ks < 4; ++ks) {
            bf16x8 bfr[4];
#pragma unroll
            for (int j = 0; j < 4; ++j)
                bfr[j] = *(const bf16x8*)(Btg2 + ((s * 16 + j * 4 + ks) << 9) + lofs);
#pragma unroll
            for (int j = 0; j < 4; ++j)
                acc[j] = __builtin_amdgcn_mfma_f32_16x16x32_bf16(af[ks], bfr[j], acc[j], 0, 0, 0);
        }
#pragma unroll
        for (int reg = 0; reg < 4; ++reg) {
            int r = m0 + quad * 4 + reg;
            if (full || r < N) {
                unsigned pk = (unsigned)__builtin_amdgcn_cvt_pk_fp8_f32(acc[0][reg], acc[1][reg], 0, false);
                pk = (unsigned)__builtin_amdgcn_cvt_pk_fp8_f32(acc[2][reg], acc[3][reg], (int)pk, true);
                *(unsigned*)(Hh8 + ((size_t)r << 8) + (s * 16 + n15) * 4) = pk;
            }
        }
    }

    // ---- Hr: tiles 4..7 (j = head) + gat_bias ----
#pragma unroll
    for (int s = 0; s < 4; ++s) {
        f32x4 acc[4] = {};
#pragma unroll
        for (int ks = 0; ks < 4; ++ks) {
            bf16x8 bfr[4];
#pragma unroll
            for (int j = 0; j < 4; ++j)
                bfr[j] = *(const bf16x8*)(Btg2 + (((4 + s) * 16 + j * 4 + ks) << 9) + lofs);
#pragma unroll
            for (int j = 0; j < 4; ++j)
                acc[j] = __builtin_amdgcn_mfma_f32_16x16x32_bf16(af[ks], bfr[j], acc[j], 0, 0, 0);
        }
        float b0 = gat_bias[0 * 64 + s * 16 + n15];
        float b1 = gat_bias[1 * 64 + s * 16 + n15];
        float b2 = gat_bias[2 * 64 + s * 16 + n15];
        float b3 = gat_bias[3 * 64 + s * 16 + n15];
#pragma unroll
        for (int reg = 0; reg < 4; ++reg) {
            int r = m0 + quad * 4 + reg;
            if (full || r < N) {
                unsigned pk = (unsigned)__builtin_amdgcn_cvt_pk_fp8_f32(acc[0][reg] + b0, acc[1][reg] + b1, 0, false);
                pk = (unsigned)__builtin_amdgcn_cvt_pk_fp8_f32(acc[2][reg] + b2, acc[3][reg] + b3, (int)pk, true);
                *(unsigned*)(Hr8 + ((size_t)r << 8) + (s * 16 + n15) * 4) = pk;
            }
        }
    }

    // ---- Rres: tile 8 (outer residual + res_b, bf16) ----
    {
        f32x4 acc[4] = {};
#pragma unroll
        for (int ks = 0; ks < 4; ++ks) {
            bf16x8 bfr[4];
#pragma unroll
            for (int j = 0; j < 4; ++j)
                bfr[j] = *(const bf16x8*)(Btg2 + ((8 * 16 + j * 4 + ks) << 9) + lofs);
#pragma unroll
            for (int j = 0; j < 4; ++j)
                acc[j] = __builtin_amdgcn_mfma_f32_16x16x32_bf16(af[ks], bfr[j], acc[j], 0, 0, 0);
        }
#pragma unroll
        for (int reg = 0; reg < 4; ++reg) {
            int r = m0 + quad * 4 + reg;
            if (full || r < N) {
#pragma unroll
                for (int j = 0; j < 4; ++j)
                    Rres[(size_t)r * OUTD + j * 16 + n15] = f2bf(acc[j][reg] + res_b[j * 16 + n15]);
            }
        }
    }

    // ---- el/er: tile 9, j=0 (cols 576..591 = 4 el, 4 er, 8 zero) ----
    {
        f32x4 acc2 = {};
#pragma unroll
        for (int ks = 0; ks < 4; ++ks) {
            bf16x8 b = *(const bf16x8*)(Btg2 + ((9 * 16 + ks) << 9) + lofs);
            acc2 = __builtin_amdgcn_mfma_f32_16x16x32_bf16(af[ks], b, acc2, 0, 0, 0);
        }
#pragma unroll
        for (int reg = 0; reg < 4; ++reg) {
            int r = m0 + quad * 4 + reg;
            if ((full || r < N) && n15 < 8) {
                float v = acc2[reg];
                if (n15 < 4) el[(size_t)r * 4 + n15] = v;
                else         er[(size_t)r * 4 + (n15 - 4)] = v;
            }
        }
    }
}

// ============ hierarchical scan ============
__global__ __launch_bounds__(256) void scanA_kernel(const int* __restrict__ degree,
                                                    int* __restrict__ excl,
                                                    int* __restrict__ blocksum, int N) {
    __shared__ int sm[256];
    int t = threadIdx.x;
    int i = blockIdx.x * 256 + t;
    int d = (i < N) ? degree[i] : 0;
    sm[t] = d; __syncthreads();
    for (int off = 1; off < 256; off <<= 1) {
        int v = (t >= off) ? sm[t - off] : 0;
        __syncthreads();
        sm[t] += v;
        __syncthreads();
    }
    if (i < N) excl[i] = sm[t] - d;
    if (t == 255) blocksum[blockIdx.x] = sm[255];
}

__global__ __launch_bounds__(256) void scanB_kernel(const int* __restrict__ blocksum,
                                                    int* __restrict__ base, int nb) {
    __shared__ int sm[256];
    int t = threadIdx.x;
    int d = (t < nb) ? blocksum[t] : 0;
    sm[t] = d; __syncthreads();
    for (int off = 1; off < 256; off <<= 1) {
        int v = (t >= off) ? sm[t - off] : 0;
        __syncthreads();
        sm[t] += v;
        __syncthreads();
    }
    if (t < nb) base[t] = sm[t] - d;
}

// ============ lean scatter: usrc_sorted[p] = src<<8 (scores computed in agg) ============
__global__ void scatter_kernel(const int* __restrict__ src, const int* __restrict__ dst,
                               const int* __restrict__ rank, const int* __restrict__ excl,
                               const int* __restrict__ base,
                               unsigned* __restrict__ usrc_sorted, int E) {
    int e = blockIdx.x * 256 + threadIdx.x;
    if (e >= E) return;
    int d = dst[e];
    int p = excl[d] + base[d >> 8] + rank[e];
    usrc_sorted[p] = (unsigned)src[e] << 8;
}

// ============ aggregation + epilogue: in-kernel scores (el is L2-resident), readlane bcast ============
__global__ __launch_bounds__(256) void agg_kernel(
    const unsigned char* __restrict__ Hh8, const unsigned char* __restrict__ Hr8,
    const unsigned short* __restrict__ Rres, const float* __restrict__ el,
    const float* __restrict__ er,
    const int* __restrict__ excl, const int* __restrict__ base,
    const unsigned* __restrict__ usrc_sorted,
    const float* __restrict__ conv_w, const float* __restrict__ conv_b,
    float* __restrict__ y, int N, int E)
{
    int wave = threadIdx.x >> 6, lane = threadIdx.x & 63;
    int v = blockIdx.x * 4 + wave;
    if (v >= N) return;
    int b  = excl[v] + base[v >> 8];
    int e2 = (v + 1 < N) ? (excl[v + 1] + base[(v + 1) >> 8]) : E;
    int deg = e2 - b;

    float4 rv = *(const float4*)(er + (size_t)v * 4);
    const unsigned char* hbase = Hh8 + lane * 4;
    float a0 = 0.f, a1 = 0.f, a2 = 0.f, a3 = 0.f;
    float p0 = 0.f, p1 = 0.f, p2 = 0.f, p3 = 0.f;

    for (int i0 = 0; i0 < deg; i0 += 64) {
        int j = i0 + lane;
        unsigned ux = 0, s01 = 0, s23 = 0;
        if (j < deg) {
            ux = usrc_sorted[b + j];
            float4 l = *(const float4*)(el + ((size_t)(ux >> 8)) * 4);   // L2-hot (800 KB)
            float x, s0, s1, s2, s3;
            x = l.x + rv.x; x = x > 0.f ? x : NEG_SLOPE * x; s0 = __expf(x);
            x = l.y + rv.y; x = x > 0.f ? x : NEG_SLOPE * x; s1 = __expf(x);
            x = l.z + rv.z; x = x > 0.f ? x : NEG_SLOPE * x; s2 = __expf(x);
            x = l.w + rv.w; x = x > 0.f ? x : NEG_SLOPE * x; s3 = __expf(x);
            p0 += s0; p1 += s1; p2 += s2; p3 += s3;   // fp32 denominators
            s01 = (unsigned)f2bf(s0) | ((unsigned)f2bf(s1) << 16);
            s23 = (unsigned)f2bf(s2) | ((unsigned)f2bf(s3) << 16);
        }
        int cl = deg - i0; if (cl > 64) cl = 64;
        int jj = 0;
        for (; jj + 1 < cl; jj += 2) {
            unsigned uA   = (unsigned)__builtin_amdgcn_readlane((int)ux, jj);
            unsigned sA01 = (unsigned)__builtin_amdgcn_readlane((int)s01, jj);
            unsigned sA23 = (unsigned)__builtin_amdgcn_readlane((int)s23, jj);
            unsigned uB   = (unsigned)__builtin_amdgcn_readlane((int)ux, jj + 1);
            unsigned sB01 = (unsigned)__builtin_amdgcn_readlane((int)s01, jj + 1);
            unsigned sB23 = (unsigned)__builtin_amdgcn_readlane((int)s23, jj + 1);
            unsigned hvA = *(const unsigned*)(hbase + uA);
            unsigned hvB = *(const unsigned*)(hbase + uB);
            f32x2 loA = __builtin_amdgcn_cvt_pk_f32_fp8(hvA, false);
            f32x2 hiA = __builtin_amdgcn_cvt_pk_f32_fp8(hvA, true);
            f32x2 loB = __builtin_amdgcn_cvt_pk_f32_fp8(hvB, false);
            f32x2 hiB = __builtin_amdgcn_cvt_pk_f32_fp8(hvB, true);
            a0 += bf2f((unsigned short)(sA01 & 0xffff)) * loA.x;
            a1 += bf2f((unsigned short)(sA01 >> 16))    * loA.y;
            a2 += bf2f((unsigned short)(sA23 & 0xffff)) * hiA.x;
            a3 += bf2f((unsigned short)(sA23 >> 16))    * hiA.y;
            a0 += bf2f((unsigned short)(sB01 & 0xffff)) * loB.x;
            a1 += bf2f((unsigned short)(sB01 >> 16))    * loB.y;
            a2 += bf2f((unsigned short)(sB23 & 0xffff)) * hiB.x;
            a3 += bf2f((unsigned short)(sB23 >> 16))    * hiB.y;
        }
        if (jj < cl) {
            unsigned uA   = (unsigned)__builtin_amdgcn_readlane((int)ux, jj);
            unsigned sA01 = (unsigned)__builtin_amdgcn_readlane((int)s01, jj);
            unsigned sA23 = (unsigned)__builtin_amdgcn_readlane((int)s23, jj);
            unsigned hvA = *(const unsigned*)(hbase + uA);
            f32x2 loA = __builtin_amdgcn_cvt_pk_f32_fp8(hvA, false);
            f32x2 hiA = __builtin_amdgcn_cvt_pk_f32_fp8(hvA, true);
            a0 += bf2f((unsigned short)(sA01 & 0xffff)) * loA.x;
            a1 += bf2f((unsigned short)(sA01 >> 16))    * loA.y;
            a2 += bf2f((unsigned short)(sA23 & 0xffff)) * hiA.x;
            a3 += bf2f((unsigned short)(sA23 >> 16))    * hiA.y;
        }
    }
#pragma unroll
    for (int off = 1; off < 64; off <<= 1) {
        p0 += __shfl_xor(p0, off); p1 += __shfl_xor(p1, off);
        p2 += __shfl_xor(p2, off); p3 += __shfl_xor(p3, off);
    }
    float r0 = 1.f / (p0 + 1e-16f), r1 = 1.f / (p1 + 1e-16f);
    float r2 = 1.f / (p2 + 1e-16f), r3 = 1.f / (p3 + 1e-16f);

    unsigned hr = *(const unsigned*)(Hr8 + ((size_t)v << 8) + lane * 4);
    f32x2 rlo = __builtin_amdgcn_cvt_pk_f32_fp8(hr, false);
    f32x2 rhi = __builtin_amdgcn_cvt_pk_f32_fp8(hr, true);
    float resv = bf2f(Rres[(size_t)v * OUTD + lane]);
    float yv = conv_b[0] + (resv > 0.f ? resv : 0.f);
    float tt;
    tt = a0 * r0 + rlo.x; tt = tt > 0.f ? tt : 0.f; yv += conv_w[0] * tt;
    tt = a1 * r1 + rlo.y; tt = tt > 0.f ? tt : 0.f; yv += conv_w[1] * tt;
    tt = a2 * r2 + rhi.x; tt = tt > 0.f ? tt : 0.f; yv += conv_w[2] * tt;
    tt = a3 * r3 + rhi.y; tt = tt > 0.f ? tt : 0.f; yv += conv_w[3] * tt;
    y[(size_t)v * OUTD + lane] = yv;
}

// ============ BN tail ============
__global__ __launch_bounds__(256) void bn_partial_kernel(const float* __restrict__ y,
                                                         float* __restrict__ bnsum,
                                                         float* __restrict__ bnsumsq, int total) {
    __shared__ float smem[256];
    int t = threadIdx.x;
    size_t idx = (size_t)blockIdx.x * 256 + t;
    size_t stride = (size_t)gridDim.x * 256;
    float sum = 0.f, sq = 0.f;
    for (; idx < (size_t)total; idx += stride) {
        float v = y[idx];
        sum += v; sq += v * v;
    }
    int d = t & 63;
    smem[t] = sum; __syncthreads();
    if (t < 64) atomicAdd(bnsum + d, smem[t] + smem[t + 64] + smem[t + 128] + smem[t + 192]);
    __syncthreads();
    smem[t] = sq; __syncthreads();
    if (t < 64) atomicAdd(bnsumsq + d, smem[t] + smem[t + 64] + smem[t + 128] + smem[t + 192]);
}

__global__ void norm_kernel(const float* __restrict__ y,
                            const float* __restrict__ bnsum, const float* __restrict__ bnsumsq,
                            const float* __restrict__ gamma, const float* __restrict__ beta,
                            float* __restrict__ out, int total4, float invN) {
    int idx = blockIdx.x * blockDim.x + threadIdx.x;
    if (idx >= total4) return;
    float4 v = *(const float4*)(y + (size_t)idx * 4);
    int d = (idx * 4) & 63;
    float4 o;
#pragma unroll
    for (int k = 0; k < 4; ++k) {
        float mean = bnsum[d + k] * invN;
        float var = bnsumsq[d + k] * invN - mean * mean;
        float sc = gamma[d + k] * rsqrtf(var + BN_EPS);
        float sh = beta[d + k] - mean * sc;
        (&o.x)[k] = (&v.x)[k] * sc + sh;
    }
    *(float4*)(out + (size_t)idx * 4) = o;
}

// ============ launch ============
extern "C" void kernel_launch(void* const* d_in, const int* in_sizes, int n_in,
                              void* d_out, int out_size, void* d_ws, size_t ws_size,
                              hipStream_t stream) {
    const float* node_feats = (const float*)d_in[0];
    const float* W_fc       = (const float*)d_in[1];
    const float* attn_l     = (const float*)d_in[2];
    const float* attn_r     = (const float*)d_in[3];
    const float* gat_res_w  = (const float*)d_in[4];
    const float* gat_bias   = (const float*)d_in[5];
    const float* conv_w     = (const float*)d_in[6];
    const float* conv_b     = (const float*)d_in[7];
    const float* res_w      = (const float*)d_in[8];
    const float* res_b      = (const float*)d_in[9];
    const float* bn_gamma   = (const float*)d_in[10];
    const float* bn_beta    = (const float*)d_in[11];
    const int*   src        = (const int*)d_in[12];
    const int*   dst        = (const int*)d_in[13];

    const int N = in_sizes[0] / IN_F;
    const int E = in_sizes[12];
    const int nb = (N + 255) / 256;
    const int T = (N + 15) / 16;
    const int Gblocks = (T + 3) / 4;

    char* ws = (char*)d_ws;
    size_t off = 0;
    auto alloc = [&](size_t bytes) -> void* {
        void* p = (void*)(ws + off);
        off += (bytes + 255) & ~(size_t)255;
        return p;
    };

    // --- zero zone ---
    int*   degree  = (int*)alloc((size_t)N * 4);
    float* bnsum   = (float*)alloc(64 * 4);
    float* bnsumsq = (float*)alloc(64 * 4);
    size_t zero_bytes = off;
    // --- rest ---
    int*            rank        = (int*)alloc((size_t)E * 4);
    int*            excl        = (int*)alloc((size_t)N * 4);
    int*            blocksum    = (int*)alloc(256 * 4);
    int*            base        = (int*)alloc(256 * 4);
    unsigned*       usrc_sorted = (unsigned*)alloc((size_t)E * 4);
    unsigned short* Btg2        = (unsigned short*)alloc((size_t)10 * 16 * 512 * 2);  // 10 tiles
    unsigned char*  Hh8         = (unsigned char*)alloc((size_t)N * 256);
    unsigned char*  Hr8         = (unsigned char*)alloc((size_t)N * 256);
    unsigned short* Rres        = (unsigned short*)alloc((size_t)N * OUTD * 2);
    float*          el          = (float*)alloc((size_t)N * 4 * 4);
    float*          er          = (float*)alloc((size_t)N * 4 * 4);
    float*          y           = (float*)alloc((size_t)N * OUTD * 4);
    (void)ws_size; (void)n_in; (void)out_size;

    hipMemsetAsync(d_ws, 0, zero_bytes, stream);

    // 0. pack B weights into fragment-ordered layout (+ folded attention vectors)
    k0_pack<<<289, 256, 0, stream>>>(W_fc, gat_res_w, res_w, attn_l, attn_r, Btg2);
    // 1. hist blocks first (t=0 overlap), then GEMM blocks
    k1_gemm<<<HISTB + Gblocks, 256, 0, stream>>>(node_feats, Btg2, gat_bias, res_b,
                                                 dst, degree, rank, Hh8, Hr8, Rres,
                                                 el, er, N, E);
    // 2. scan
    scanA_kernel<<<nb, 256, 0, stream>>>(degree, excl, blocksum, N);
    scanB_kernel<<<1, 256, 0, stream>>>(blocksum, base, nb);
    // 3. lean scatter (no score compute)
    scatter_kernel<<<(E + 255) / 256, 256, 0, stream>>>(src, dst, rank, excl, base,
                                                        usrc_sorted, E);
    // 4. aggregation + in-kernel scores + epilogue
    agg_kernel<<<(N + 3) / 4, 256, 0, stream>>>(Hh8, Hr8, Rres, el, er, excl, base,
                                                usrc_sorted, conv_w, conv_b, y, N, E);
    // 5. BN
    bn_partial_kernel<<<512, 256, 0, stream>>>(y, bnsum, bnsumsq, N * OUTD);
    norm_kernel<<<(N * OUTD / 4 + 255) / 256, 256, 0, stream>>>(y, bnsum, bnsumsq,
                                                                bn_gamma, bn_beta, (float*)d_out,
                                                                N * OUTD / 4, 1.f / (float)N);
}

// Round 12
// 233.380 us; speedup vs baseline: 1.0698x; 1.0698x over previous
//
#include <hip/hip_runtime.h>

#define IN_F   128
#define OUTD   64
#define HOUT   256      // H*OUT
#define NEG_SLOPE 0.2f
#define BN_EPS 1e-5f
#define HISTB  256      // dedicated histogram blocks — LAST in blockIdx order (R10-proven)

typedef __attribute__((ext_vector_type(8))) short bf16x8;
typedef __attribute__((ext_vector_type(4))) float f32x4;
typedef __attribute__((ext_vector_type(2))) float f32x2;

__device__ __forceinline__ unsigned short f2bf(float f) {
    union { float f; unsigned u; } v; v.f = f;
    unsigned r = (v.u + 0x7FFF + ((v.u >> 16) & 1)) >> 16;   // RNE
    return (unsigned short)r;
}
__device__ __forceinline__ float bf2f(unsigned short h) {
    union { unsigned u; float f; } v; v.u = ((unsigned)h) << 16;
    return v.f;
}

// fragment-order index for Btg2. Tiles (tt=0..9), j=0..3, ks=0..3, 16 cols (n15), 8 k (kk).
__device__ __forceinline__ int b2idx(int c, int k) {
    int tt, j;
    if (c < 256)      { tt = (c >> 4) & 3;                     j = c >> 6; }
    else if (c < 512) { int cc = c - 256; tt = 4 + ((cc >> 4) & 3); j = cc >> 6; }
    else if (c < 576) { int cc = c - 512; tt = 8;              j = cc >> 4; }
    else              { tt = 9;                                j = 0; }
    int n15 = c & 15;
    int ks = k >> 5, qd = (k >> 3) & 3, kk = k & 7;
    return ((((tt * 4 + j) * 4 + ks) * 64) + qd * 16 + n15) * 8 + kk;
}

// ============ K0: pack weights -> Btg2 (fragment-ordered bf16) ============
__global__ __launch_bounds__(256) void k0_pack(
    const float* __restrict__ W_fc, const float* __restrict__ W_gres,
    const float* __restrict__ W_res,
    const float* __restrict__ attn_l, const float* __restrict__ attn_r,
    unsigned short* __restrict__ Btg2)
{
    int bid = blockIdx.x, t = threadIdx.x;
    if (bid < 288) {
        int idx = bid * 256 + t;          // c*128 + k, c < 576
        int c = idx >> 7, k = idx & 127;
        float v;
        if (c < 256)      v = W_fc[k * HOUT + c];
        else if (c < 512) v = W_gres[k * HOUT + (c - 256)];
        else              v = W_res[k * OUTD + (c - 512)];
        Btg2[b2idx(c, k)] = f2bf(v);
        return;
    }
    for (int p = t; p < 512; p += 256) {
        int h = p >> 7, k = p & 127;
        float sl = 0.f, sr = 0.f;
        for (int d = 0; d < 64; ++d) {
            float wv = W_fc[k * HOUT + h * 64 + d];
            sl += wv * attn_l[h * 64 + d];
            sr += wv * attn_r[h * 64 + d];
        }
        Btg2[b2idx(576 + h, k)] = f2bf(sl);
        Btg2[b2idx(580 + h, k)] = f2bf(sr);
    }
    for (int p = t; p < 8 * 128; p += 256) {
        int c = 584 + (p >> 7), k = p & 127;
        Btg2[b2idx(c, k)] = 0;
    }
}

// ============ K1: GEMM blocks first, hist blocks last (R10-proven ordering) ============
__global__ __launch_bounds__(256) void k1_gemm(
    const float* __restrict__ A, const unsigned short* __restrict__ Btg2,
    const float* __restrict__ gat_bias, const float* __restrict__ res_b,
    const int* __restrict__ dst, int* __restrict__ degree, int* __restrict__ rank,
    unsigned char* __restrict__ Hh8, unsigned char* __restrict__ Hr8,
    unsigned short* __restrict__ Rres,
    float* __restrict__ el, float* __restrict__ er,
    int N, int E, int Gblocks)
{
    int t = threadIdx.x;

    if (blockIdx.x >= Gblocks) {
        int ht = (blockIdx.x - Gblocks) * 256 + t;
        for (int e = ht; e < E; e += HISTB * 256)
            rank[e] = atomicAdd(degree + dst[e], 1);
        return;
    }

    int w = t >> 6, lane = t & 63, quad = lane >> 4, n15 = lane & 15;
    int gw = blockIdx.x * 4 + w;
    int T = (N + 15) / 16;
    if (gw >= T) return;

    int m0 = gw * 16;
    bool full = (m0 + 16 <= N);
    int lofs = (quad * 16 + n15) * 8;

    bf16x8 af[4];
    {
        int r = m0 + n15;
#pragma unroll
        for (int ks = 0; ks < 4; ++ks) {
            float4 v0 = make_float4(0.f, 0.f, 0.f, 0.f), v1 = v0;
            if (r < N) {
                const float* ap = A + (size_t)r * IN_F + ks * 32 + quad * 8;
                v0 = *(const float4*)ap;
                v1 = *(const float4*)(ap + 4);
            }
            bf16x8 o;
            o[0] = f2bf(v0.x); o[1] = f2bf(v0.y); o[2] = f2bf(v0.z); o[3] = f2bf(v0.w);
            o[4] = f2bf(v1.x); o[5] = f2bf(v1.y); o[6] = f2bf(v1.z); o[7] = f2bf(v1.w);
            af[ks] = o;
        }
    }

    // ---- Hh: tiles 0..3 (j = head) ----
#pragma unroll
    for (int s = 0; s < 4; ++s) {
        f32x4 acc[4] = {};
#pragma unroll
        for (int ks = 0; ks < 4; ++ks) {
            bf16x8 bfr[4];
#pragma unroll
            for (int j = 0; j < 4; ++j)
                bfr[j] = *(const bf16x8*)(Btg2 + ((s * 16 + j * 4 + ks) << 9) + lofs);
#pragma unroll
            for (int j = 0; j < 4; ++j)
                acc[j] = __builtin_amdgcn_mfma_f32_16x16x32_bf16(af[ks], bfr[j], acc[j], 0, 0, 0);
        }
#pragma unroll
        for (int reg = 0; reg < 4; ++reg) {
            int r = m0 + quad * 4 + reg;
            if (full || r < N) {
                unsigned pk = (unsigned)__builtin_amdgcn_cvt_pk_fp8_f32(acc[0][reg], acc[1][reg], 0, false);
                pk = (unsigned)__builtin_amdgcn_cvt_pk_fp8_f32(acc[2][reg], acc[3][reg], (int)pk, true);
                *(unsigned*)(Hh8 + ((size_t)r << 8) + (s * 16 + n15) * 4) = pk;
            }
        }
    }

    // ---- Hr: tiles 4..7 (j = head) + gat_bias ----
#pragma unroll
    for (int s = 0; s < 4; ++s) {
        f32x4 acc[4] = {};
#pragma unroll
        for (int ks = 0; ks < 4; ++ks) {
            bf16x8 bfr[4];
#pragma unroll
            for (int j = 0; j < 4; ++j)
                bfr[j] = *(const bf16x8*)(Btg2 + (((4 + s) * 16 + j * 4 + ks) << 9) + lofs);
#pragma unroll
            for (int j = 0; j < 4; ++j)
                acc[j] = __builtin_amdgcn_mfma_f32_16x16x32_bf16(af[ks], bfr[j], acc[j], 0, 0, 0);
        }
        float b0 = gat_bias[0 * 64 + s * 16 + n15];
        float b1 = gat_bias[1 * 64 + s * 16 + n15];
        float b2 = gat_bias[2 * 64 + s * 16 + n15];
        float b3 = gat_bias[3 * 64 + s * 16 + n15];
#pragma unroll
        for (int reg = 0; reg < 4; ++reg) {
            int r = m0 + quad * 4 + reg;
            if (full || r < N) {
                unsigned pk = (unsigned)__builtin_amdgcn_cvt_pk_fp8_f32(acc[0][reg] + b0, acc[1][reg] + b1, 0, false);
                pk = (unsigned)__builtin_amdgcn_cvt_pk_fp8_f32(acc[2][reg] + b2, acc[3][reg] + b3, (int)pk, true);
                *(unsigned*)(Hr8 + ((size_t)r << 8) + (s * 16 + n15) * 4) = pk;
            }
        }
    }

    // ---- Rres: tile 8 ----
    {
        f32x4 acc[4] = {};
#pragma unroll
        for (int ks = 0; ks < 4; ++ks) {
            bf16x8 bfr[4];
#pragma unroll
            for (int j = 0; j < 4; ++j)
                bfr[j] = *(const bf16x8*)(Btg2 + ((8 * 16 + j * 4 + ks) << 9) + lofs);
#pragma unroll
            for (int j = 0; j < 4; ++j)
                acc[j] = __builtin_amdgcn_mfma_f32_16x16x32_bf16(af[ks], bfr[j], acc[j], 0, 0, 0);
        }
#pragma unroll
        for (int reg = 0; reg < 4; ++reg) {
            int r = m0 + quad * 4 + reg;
            if (full || r < N) {
#pragma unroll
                for (int j = 0; j < 4; ++j)
                    Rres[(size_t)r * OUTD + j * 16 + n15] = f2bf(acc[j][reg] + res_b[j * 16 + n15]);
            }
        }
    }

    // ---- el/er: tile 9 ----
    {
        f32x4 acc2 = {};
#pragma unroll
        for (int ks = 0; ks < 4; ++ks) {
            bf16x8 b = *(const bf16x8*)(Btg2 + ((9 * 16 + ks) << 9) + lofs);
            acc2 = __builtin_amdgcn_mfma_f32_16x16x32_bf16(af[ks], b, acc2, 0, 0, 0);
        }
#pragma unroll
        for (int reg = 0; reg < 4; ++reg) {
            int r = m0 + quad * 4 + reg;
            if ((full || r < N) && n15 < 8) {
                float v = acc2[reg];
                if (n15 < 4) el[(size_t)r * 4 + n15] = v;
                else         er[(size_t)r * 4 + (n15 - 4)] = v;
            }
        }
    }
}

// ============ scanA: per-256 chunk exclusive scans + chunk sums ============
__global__ __launch_bounds__(256) void scanA_kernel(const int* __restrict__ degree,
                                                    int* __restrict__ excl,
                                                    int* __restrict__ blocksum, int N) {
    __shared__ int sm[256];
    int t = threadIdx.x;
    int i = blockIdx.x * 256 + t;
    int d = (i < N) ? degree[i] : 0;
    sm[t] = d; __syncthreads();
    for (int off = 1; off < 256; off <<= 1) {
        int v = (t >= off) ? sm[t - off] : 0;
        __syncthreads();
        sm[t] += v;
        __syncthreads();
    }
    if (i < N) excl[i] = sm[t] - d;
    if (t == 255) blocksum[blockIdx.x] = sm[255];
}

// ============ scatter (+inline scanB): usrc_sorted[p] = src<<8 ============
__global__ __launch_bounds__(256) void scatter_kernel(
    const int* __restrict__ src, const int* __restrict__ dst,
    const int* __restrict__ rank, const int* __restrict__ excl,
    const int* __restrict__ blocksum,
    unsigned* __restrict__ usrc_sorted, int E, int nb) {
    __shared__ int sm[256];
    __shared__ int base_lds[256];
    int t = threadIdx.x;
    int d0 = (t < nb) ? blocksum[t] : 0;
    sm[t] = d0; __syncthreads();
    for (int off = 1; off < 256; off <<= 1) {
        int v = (t >= off) ? sm[t - off] : 0;
        __syncthreads();
        sm[t] += v;
        __syncthreads();
    }
    base_lds[t] = sm[t] - d0;
    __syncthreads();

    int e = blockIdx.x * 256 + t;
    if (e >= E) return;
    int d = dst[e];
    int p = excl[d] + base_lds[d >> 8] + rank[e];
    usrc_sorted[p] = (unsigned)src[e] << 8;
}

// ============ aggregation + in-kernel scores + epilogue + fused BN partials ============
__global__ __launch_bounds__(256) void agg_kernel(
    const unsigned char* __restrict__ Hh8, const unsigned char* __restrict__ Hr8,
    const unsigned short* __restrict__ Rres, const float* __restrict__ el,
    const float* __restrict__ er,
    const int* __restrict__ excl, const int* __restrict__ base,
    const unsigned* __restrict__ usrc_sorted,
    const float* __restrict__ conv_w, const float* __restrict__ conv_b,
    float* __restrict__ y, float* __restrict__ bnsum8, float* __restrict__ bnsq8,
    int N, int E)
{
    __shared__ float smem[256];
    __shared__ float smem2[256];
    int t = threadIdx.x;
    int wave = t >> 6, lane = t & 63;
    int v = blockIdx.x * 4 + wave;

    float yv = 0.f;
    if (v < N) {
        int b  = excl[v] + base[v >> 8];
        int e2 = (v + 1 < N) ? (excl[v + 1] + base[(v + 1) >> 8]) : E;
        int deg = e2 - b;

        float4 rv = *(const float4*)(er + (size_t)v * 4);
        const unsigned char* hbase = Hh8 + lane * 4;
        float a0 = 0.f, a1 = 0.f, a2 = 0.f, a3 = 0.f;
        float p0 = 0.f, p1 = 0.f, p2 = 0.f, p3 = 0.f;

        for (int i0 = 0; i0 < deg; i0 += 64) {
            int j = i0 + lane;
            unsigned ux = 0, s01 = 0, s23 = 0;
            if (j < deg) {
                ux = usrc_sorted[b + j];
                float4 l = *(const float4*)(el + ((size_t)(ux >> 8)) * 4);   // L2-hot (800 KB)
                float x, s0, s1, s2, s3;
                x = l.x + rv.x; x = x > 0.f ? x : NEG_SLOPE * x; s0 = __expf(x);
                x = l.y + rv.y; x = x > 0.f ? x : NEG_SLOPE * x; s1 = __expf(x);
                x = l.z + rv.z; x = x > 0.f ? x : NEG_SLOPE * x; s2 = __expf(x);
                x = l.w + rv.w; x = x > 0.f ? x : NEG_SLOPE * x; s3 = __expf(x);
                p0 += s0; p1 += s1; p2 += s2; p3 += s3;
                s01 = (unsigned)f2bf(s0) | ((unsigned)f2bf(s1) << 16);
                s23 = (unsigned)f2bf(s2) | ((unsigned)f2bf(s3) << 16);
            }
            int cl = deg - i0; if (cl > 64) cl = 64;
            int jj = 0;
            for (; jj + 1 < cl; jj += 2) {
                unsigned uA   = (unsigned)__builtin_amdgcn_readlane((int)ux, jj);
                unsigned sA01 = (unsigned)__builtin_amdgcn_readlane((int)s01, jj);
                unsigned sA23 = (unsigned)__builtin_amdgcn_readlane((int)s23, jj);
                unsigned uB   = (unsigned)__builtin_amdgcn_readlane((int)ux, jj + 1);
                unsigned sB01 = (unsigned)__builtin_amdgcn_readlane((int)s01, jj + 1);
                unsigned sB23 = (unsigned)__builtin_amdgcn_readlane((int)s23, jj + 1);
                unsigned hvA = *(const unsigned*)(hbase + uA);
                unsigned hvB = *(const unsigned*)(hbase + uB);
                f32x2 loA = __builtin_amdgcn_cvt_pk_f32_fp8(hvA, false);
                f32x2 hiA = __builtin_amdgcn_cvt_pk_f32_fp8(hvA, true);
                f32x2 loB = __builtin_amdgcn_cvt_pk_f32_fp8(hvB, false);
                f32x2 hiB = __builtin_amdgcn_cvt_pk_f32_fp8(hvB, true);
                a0 += bf2f((unsigned short)(sA01 & 0xffff)) * loA.x;
                a1 += bf2f((unsigned short)(sA01 >> 16))    * loA.y;
                a2 += bf2f((unsigned short)(sA23 & 0xffff)) * hiA.x;
                a3 += bf2f((unsigned short)(sA23 >> 16))    * hiA.y;
                a0 += bf2f((unsigned short)(sB01 & 0xffff)) * loB.x;
                a1 += bf2f((unsigned short)(sB01 >> 16))    * loB.y;
                a2 += bf2f((unsigned short)(sB23 & 0xffff)) * hiB.x;
                a3 += bf2f((unsigned short)(sB23 >> 16))    * hiB.y;
            }
            if (jj < cl) {
                unsigned uA   = (unsigned)__builtin_amdgcn_readlane((int)ux, jj);
                unsigned sA01 = (unsigned)__builtin_amdgcn_readlane((int)s01, jj);
                unsigned sA23 = (unsigned)__builtin_amdgcn_readlane((int)s23, jj);
                unsigned hvA = *(const unsigned*)(hbase + uA);
                f32x2 loA = __builtin_amdgcn_cvt_pk_f32_fp8(hvA, false);
                f32x2 hiA = __builtin_amdgcn_cvt_pk_f32_fp8(hvA, true);
                a0 += bf2f((unsigned short)(sA01 & 0xffff)) * loA.x;
                a1 += bf2f((unsigned short)(sA01 >> 16))    * loA.y;
                a2 += bf2f((unsigned short)(sA23 & 0xffff)) * hiA.x;
                a3 += bf2f((unsigned short)(sA23 >> 16))    * hiA.y;
            }
        }
#pragma unroll
        for (int off = 1; off < 64; off <<= 1) {
            p0 += __shfl_xor(p0, off); p1 += __shfl_xor(p1, off);
            p2 += __shfl_xor(p2, off); p3 += __shfl_xor(p3, off);
        }
        float r0 = 1.f / (p0 + 1e-16f), r1 = 1.f / (p1 + 1e-16f);
        float r2 = 1.f / (p2 + 1e-16f), r3 = 1.f / (p3 + 1e-16f);

        unsigned hr = *(const unsigned*)(Hr8 + ((size_t)v << 8) + lane * 4);
        f32x2 rlo = __builtin_amdgcn_cvt_pk_f32_fp8(hr, false);
        f32x2 rhi = __builtin_amdgcn_cvt_pk_f32_fp8(hr, true);
        float resv = bf2f(Rres[(size_t)v * OUTD + lane]);
        yv = conv_b[0] + (resv > 0.f ? resv : 0.f);
        float tt;
        tt = a0 * r0 + rlo.x; tt = tt > 0.f ? tt : 0.f; yv += conv_w[0] * tt;
        tt = a1 * r1 + rlo.y; tt = tt > 0.f ? tt : 0.f; yv += conv_w[1] * tt;
        tt = a2 * r2 + rhi.x; tt = tt > 0.f ? tt : 0.f; yv += conv_w[2] * tt;
        tt = a3 * r3 + rhi.y; tt = tt > 0.f ? tt : 0.f; yv += conv_w[3] * tt;
        y[(size_t)v * OUTD + lane] = yv;
    }

    // ---- fused BN partials: per-block LDS reduce -> 8-way split atomics ----
    smem[t] = yv;
    smem2[t] = yv * yv;
    __syncthreads();
    if (t < 64) {
        float s = smem[t] + smem[t + 64] + smem[t + 128] + smem[t + 192];
        float q = smem2[t] + smem2[t + 64] + smem2[t + 128] + smem2[t + 192];
        int c = (blockIdx.x & 7) << 6;
        atomicAdd(bnsum8 + c + t, s);
        atomicAdd(bnsq8 + c + t, q);
    }
}

// ============ norm: fold 8-copy BN sums (per-block LDS) then normalize ============
__global__ __launch_bounds__(256) void norm_kernel(
    const float* __restrict__ y,
    const float* __restrict__ bnsum8, const float* __restrict__ bnsq8,
    const float* __restrict__ gamma, const float* __restrict__ beta,
    float* __restrict__ out, int total4, float invN) {
    __shared__ float scale[64], shift[64];
    int t = threadIdx.x;
    if (t < 64) {
        float s = 0.f, q = 0.f;
#pragma unroll
        for (int c = 0; c < 8; ++c) { s += bnsum8[c * 64 + t]; q += bnsq8[c * 64 + t]; }
        float mean = s * invN;
        float var = q * invN - mean * mean;
        float sc = gamma[t] * rsqrtf(var + BN_EPS);
        scale[t] = sc;
        shift[t] = beta[t] - mean * sc;
    }
    __syncthreads();
    int idx = blockIdx.x * blockDim.x + t;
    if (idx >= total4) return;
    float4 v = *(const float4*)(y + (size_t)idx * 4);
    int d = (idx * 4) & 63;
    float4 o;
    o.x = v.x * scale[d + 0] + shift[d + 0];
    o.y = v.y * scale[d + 1] + shift[d + 1];
    o.z = v.z * scale[d + 2] + shift[d + 2];
    o.w = v.w * scale[d + 3] + shift[d + 3];
    *(float4*)(out + (size_t)idx * 4) = o;
}

// ============ launch ============
extern "C" void kernel_launch(void* const* d_in, const int* in_sizes, int n_in,
                              void* d_out, int out_size, void* d_ws, size_t ws_size,
                              hipStream_t stream) {
    const float* node_feats = (const float*)d_in[0];
    const float* W_fc       = (const float*)d_in[1];
    const float* attn_l     = (const float*)d_in[2];
    const float* attn_r     = (const float*)d_in[3];
    const float* gat_res_w  = (const float*)d_in[4];
    const float* gat_bias   = (const float*)d_in[5];
    const float* conv_w     = (const float*)d_in[6];
    const float* conv_b     = (const float*)d_in[7];
    const float* res_w      = (const float*)d_in[8];
    const float* res_b      = (const float*)d_in[9];
    const float* bn_gamma   = (const float*)d_in[10];
    const float* bn_beta    = (const float*)d_in[11];
    const int*   src        = (const int*)d_in[12];
    const int*   dst        = (const int*)d_in[13];

    const int N = in_sizes[0] / IN_F;
    const int E = in_sizes[12];
    const int nb = (N + 255) / 256;
    const int T = (N + 15) / 16;
    const int Gblocks = (T + 3) / 4;

    char* ws = (char*)d_ws;
    size_t off = 0;
    auto alloc = [&](size_t bytes) -> void* {
        void* p = (void*)(ws + off);
        off += (bytes + 255) & ~(size_t)255;
        return p;
    };

    // --- zero zone ---
    int*   degree  = (int*)alloc((size_t)N * 4);
    float* bnsum8  = (float*)alloc(8 * 64 * 4);
    float* bnsq8   = (float*)alloc(8 * 64 * 4);
    size_t zero_bytes = off;
    // --- rest ---
    int*            rank        = (int*)alloc((size_t)E * 4);
    int*            excl        = (int*)alloc((size_t)N * 4);
    int*            blocksum    = (int*)alloc(256 * 4);
    int*            base        = (int*)alloc(256 * 4);
    unsigned*       usrc_sorted = (unsigned*)alloc((size_t)E * 4);
    unsigned short* Btg2        = (unsigned short*)alloc((size_t)10 * 16 * 512 * 2);
    unsigned char*  Hh8         = (unsigned char*)alloc((size_t)N * 256);
    unsigned char*  Hr8         = (unsigned char*)alloc((size_t)N * 256);
    unsigned short* Rres        = (unsigned short*)alloc((size_t)N * OUTD * 2);
    float*          el          = (float*)alloc((size_t)N * 4 * 4);
    float*          er          = (float*)alloc((size_t)N * 4 * 4);
    float*          y           = (float*)alloc((size_t)N * OUTD * 4);
    (void)ws_size; (void)n_in; (void)out_size;

    hipMemsetAsync(d_ws, 0, zero_bytes, stream);

    // 0. pack B weights
    k0_pack<<<289, 256, 0, stream>>>(W_fc, gat_res_w, res_w, attn_l, attn_r, Btg2);
    // 1. GEMM blocks first, hist blocks last (R10-proven)
    k1_gemm<<<Gblocks + HISTB, 256, 0, stream>>>(node_feats, Btg2, gat_bias, res_b,
                                                 dst, degree, rank, Hh8, Hr8, Rres,
                                                 el, er, N, E, Gblocks);
    // 2. scanA (chunk scans + chunk sums)
    scanA_kernel<<<nb, 256, 0, stream>>>(degree, excl, blocksum, N);
    // 2b. base[] for agg (tiny: reuse scatter's inline scan result — compute once here too)
    //     scatter computes base inline; agg needs base[] in global — do a 1-block pass:
    //     (cheap: 1 block, same code as old scanB)
    // 3. scatter (+inline scanB)
    scatter_kernel<<<(E + 255) / 256, 256, 0, stream>>>(src, dst, rank, excl, blocksum,
                                                        usrc_sorted, E, nb);
    // base[] for agg: one small block
    {
        // reuse scanA on blocksum as a 1-block exclusive scan into base
        // (scanA writes excl-style output: base[i] = prefix-sum-exclusive of blocksum)
        scanA_kernel<<<1, 256, 0, stream>>>(blocksum, base, (int*)(base + 256 - 1) /*unused slot*/, nb);
    }
    // 4. aggregation + scores + epilogue + fused BN partials
    agg_kernel<<<(N + 3) / 4, 256, 0, stream>>>(Hh8, Hr8, Rres, el, er, excl, base,
                                                usrc_sorted, conv_w, conv_b, y,
                                                bnsum8, bnsq8, N, E);
    // 5. norm (folds BN finalize)
    norm_kernel<<<(N * OUTD / 4 + 255) / 256, 256, 0, stream>>>(y, bnsum8, bnsq8,
                                                                bn_gamma, bn_beta, (float*)d_out,
                                                                N * OUTD / 4, 1.f / (float)N);
}

// Round 13
// 225.561 us; speedup vs baseline: 1.1069x; 1.0347x over previous
//
#include <hip/hip_runtime.h>

#define IN_F   128
#define OUTD   64
#define HOUT   256      // H*OUT
#define NEG_SLOPE 0.2f
#define BN_EPS 1e-5f
#define HISTB  256      // dedicated histogram blocks — LAST in blockIdx order (R10-proven)

typedef __attribute__((ext_vector_type(8))) short bf16x8;
typedef __attribute__((ext_vector_type(4))) float f32x4;
typedef __attribute__((ext_vector_type(2))) float f32x2;

__device__ __forceinline__ unsigned short f2bf(float f) {
    union { float f; unsigned u; } v; v.f = f;
    unsigned r = (v.u + 0x7FFF + ((v.u >> 16) & 1)) >> 16;   // RNE
    return (unsigned short)r;
}
__device__ __forceinline__ float bf2f(unsigned short h) {
    union { unsigned u; float f; } v; v.u = ((unsigned)h) << 16;
    return v.f;
}
__device__ __forceinline__ float u2f(unsigned u) {
    union { unsigned u; float f; } v; v.u = u;
    return v.f;
}
__device__ __forceinline__ unsigned f2u(float f) {
    union { float f; unsigned u; } v; v.f = f;
    return v.u;
}

// fragment-order index for Btg2. Tiles (tt=0..9), j=0..3, ks=0..3, 16 cols (n15), 8 k (kk).
__device__ __forceinline__ int b2idx(int c, int k) {
    int tt, j;
    if (c < 256)      { tt = (c >> 4) & 3;                     j = c >> 6; }
    else if (c < 512) { int cc = c - 256; tt = 4 + ((cc >> 4) & 3); j = cc >> 6; }
    else if (c < 576) { int cc = c - 512; tt = 8;              j = cc >> 4; }
    else              { tt = 9;                                j = 0; }
    int n15 = c & 15;
    int ks = k >> 5, qd = (k >> 3) & 3, kk = k & 7;
    return ((((tt * 4 + j) * 4 + ks) * 64) + qd * 16 + n15) * 8 + kk;
}

// ============ K0: pack weights -> Btg2 (fragment-ordered bf16) ============
__global__ __launch_bounds__(256) void k0_pack(
    const float* __restrict__ W_fc, const float* __restrict__ W_gres,
    const float* __restrict__ W_res,
    const float* __restrict__ attn_l, const float* __restrict__ attn_r,
    unsigned short* __restrict__ Btg2)
{
    int bid = blockIdx.x, t = threadIdx.x;
    if (bid < 288) {
        int idx = bid * 256 + t;          // c*128 + k, c < 576
        int c = idx >> 7, k = idx & 127;
        float v;
        if (c < 256)      v = W_fc[k * HOUT + c];
        else if (c < 512) v = W_gres[k * HOUT + (c - 256)];
        else              v = W_res[k * OUTD + (c - 512)];
        Btg2[b2idx(c, k)] = f2bf(v);
        return;
    }
    for (int p = t; p < 512; p += 256) {
        int h = p >> 7, k = p & 127;
        float sl = 0.f, sr = 0.f;
        for (int d = 0; d < 64; ++d) {
            float wv = W_fc[k * HOUT + h * 64 + d];
            sl += wv * attn_l[h * 64 + d];
            sr += wv * attn_r[h * 64 + d];
        }
        Btg2[b2idx(576 + h, k)] = f2bf(sl);
        Btg2[b2idx(580 + h, k)] = f2bf(sr);
    }
    for (int p = t; p < 8 * 128; p += 256) {
        int c = 584 + (p >> 7), k = p & 127;
        Btg2[b2idx(c, k)] = 0;
    }
}

// ============ K1: GEMM blocks first, hist blocks last (R10-proven ordering) ============
__global__ __launch_bounds__(256) void k1_gemm(
    const float* __restrict__ A, const unsigned short* __restrict__ Btg2,
    const float* __restrict__ gat_bias, const float* __restrict__ res_b,
    const int* __restrict__ dst, int* __restrict__ degree, int* __restrict__ rank,
    unsigned char* __restrict__ Hh8, unsigned char* __restrict__ Hr8,
    unsigned short* __restrict__ Rres,
    float* __restrict__ el, float* __restrict__ er,
    int N, int E, int Gblocks)
{
    int t = threadIdx.x;

    if (blockIdx.x >= Gblocks) {
        int ht = (blockIdx.x - Gblocks) * 256 + t;
        for (int e = ht; e < E; e += HISTB * 256)
            rank[e] = atomicAdd(degree + dst[e], 1);
        return;
    }

    int w = t >> 6, lane = t & 63, quad = lane >> 4, n15 = lane & 15;
    int gw = blockIdx.x * 4 + w;
    int T = (N + 15) / 16;
    if (gw >= T) return;

    int m0 = gw * 16;
    bool full = (m0 + 16 <= N);
    int lofs = (quad * 16 + n15) * 8;

    bf16x8 af[4];
    {
        int r = m0 + n15;
#pragma unroll
        for (int ks = 0; ks < 4; ++ks) {
            float4 v0 = make_float4(0.f, 0.f, 0.f, 0.f), v1 = v0;
            if (r < N) {
                const float* ap = A + (size_t)r * IN_F + ks * 32 + quad * 8;
                v0 = *(const float4*)ap;
                v1 = *(const float4*)(ap + 4);
            }
            bf16x8 o;
            o[0] = f2bf(v0.x); o[1] = f2bf(v0.y); o[2] = f2bf(v0.z); o[3] = f2bf(v0.w);
            o[4] = f2bf(v1.x); o[5] = f2bf(v1.y); o[6] = f2bf(v1.z); o[7] = f2bf(v1.w);
            af[ks] = o;
        }
    }

    // ---- Hh: tiles 0..3 (j = head) ----
#pragma unroll
    for (int s = 0; s < 4; ++s) {
        f32x4 acc[4] = {};
#pragma unroll
        for (int ks = 0; ks < 4; ++ks) {
            bf16x8 bfr[4];
#pragma unroll
            for (int j = 0; j < 4; ++j)
                bfr[j] = *(const bf16x8*)(Btg2 + ((s * 16 + j * 4 + ks) << 9) + lofs);
#pragma unroll
            for (int j = 0; j < 4; ++j)
                acc[j] = __builtin_amdgcn_mfma_f32_16x16x32_bf16(af[ks], bfr[j], acc[j], 0, 0, 0);
        }
#pragma unroll
        for (int reg = 0; reg < 4; ++reg) {
            int r = m0 + quad * 4 + reg;
            if (full || r < N) {
                unsigned pk = (unsigned)__builtin_amdgcn_cvt_pk_fp8_f32(acc[0][reg], acc[1][reg], 0, false);
                pk = (unsigned)__builtin_amdgcn_cvt_pk_fp8_f32(acc[2][reg], acc[3][reg], (int)pk, true);
                *(unsigned*)(Hh8 + ((size_t)r << 8) + (s * 16 + n15) * 4) = pk;
            }
        }
    }

    // ---- Hr: tiles 4..7 (j = head) + gat_bias ----
#pragma unroll
    for (int s = 0; s < 4; ++s) {
        f32x4 acc[4] = {};
#pragma unroll
        for (int ks = 0; ks < 4; ++ks) {
            bf16x8 bfr[4];
#pragma unroll
            for (int j = 0; j < 4; ++j)
                bfr[j] = *(const bf16x8*)(Btg2 + (((4 + s) * 16 + j * 4 + ks) << 9) + lofs);
#pragma unroll
            for (int j = 0; j < 4; ++j)
                acc[j] = __builtin_amdgcn_mfma_f32_16x16x32_bf16(af[ks], bfr[j], acc[j], 0, 0, 0);
        }
        float b0 = gat_bias[0 * 64 + s * 16 + n15];
        float b1 = gat_bias[1 * 64 + s * 16 + n15];
        float b2 = gat_bias[2 * 64 + s * 16 + n15];
        float b3 = gat_bias[3 * 64 + s * 16 + n15];
#pragma unroll
        for (int reg = 0; reg < 4; ++reg) {
            int r = m0 + quad * 4 + reg;
            if (full || r < N) {
                unsigned pk = (unsigned)__builtin_amdgcn_cvt_pk_fp8_f32(acc[0][reg] + b0, acc[1][reg] + b1, 0, false);
                pk = (unsigned)__builtin_amdgcn_cvt_pk_fp8_f32(acc[2][reg] + b2, acc[3][reg] + b3, (int)pk, true);
                *(unsigned*)(Hr8 + ((size_t)r << 8) + (s * 16 + n15) * 4) = pk;
            }
        }
    }

    // ---- Rres: tile 8 ----
    {
        f32x4 acc[4] = {};
#pragma unroll
        for (int ks = 0; ks < 4; ++ks) {
            bf16x8 bfr[4];
#pragma unroll
            for (int j = 0; j < 4; ++j)
                bfr[j] = *(const bf16x8*)(Btg2 + ((8 * 16 + j * 4 + ks) << 9) + lofs);
#pragma unroll
            for (int j = 0; j < 4; ++j)
                acc[j] = __builtin_amdgcn_mfma_f32_16x16x32_bf16(af[ks], bfr[j], acc[j], 0, 0, 0);
        }
#pragma unroll
        for (int reg = 0; reg < 4; ++reg) {
            int r = m0 + quad * 4 + reg;
            if (full || r < N) {
#pragma unroll
                for (int j = 0; j < 4; ++j)
                    Rres[(size_t)r * OUTD + j * 16 + n15] = f2bf(acc[j][reg] + res_b[j * 16 + n15]);
            }
        }
    }

    // ---- el/er: tile 9 ----
    {
        f32x4 acc2 = {};
#pragma unroll
        for (int ks = 0; ks < 4; ++ks) {
            bf16x8 b = *(const bf16x8*)(Btg2 + ((9 * 16 + ks) << 9) + lofs);
            acc2 = __builtin_amdgcn_mfma_f32_16x16x32_bf16(af[ks], b, acc2, 0, 0, 0);
        }
#pragma unroll
        for (int reg = 0; reg < 4; ++reg) {
            int r = m0 + quad * 4 + reg;
            if ((full || r < N) && n15 < 8) {
                float v = acc2[reg];
                if (n15 < 4) el[(size_t)r * 4 + n15] = v;
                else         er[(size_t)r * 4 + (n15 - 4)] = v;
            }
        }
    }
}

// ============ scanA: per-256 chunk exclusive scans + chunk sums ============
__global__ __launch_bounds__(256) void scanA_kernel(const int* __restrict__ degree,
                                                    int* __restrict__ excl,
                                                    int* __restrict__ blocksum, int N) {
    __shared__ int sm[256];
    int t = threadIdx.x;
    int i = blockIdx.x * 256 + t;
    int d = (i < N) ? degree[i] : 0;
    sm[t] = d; __syncthreads();
    for (int off = 1; off < 256; off <<= 1) {
        int v = (t >= off) ? sm[t - off] : 0;
        __syncthreads();
        sm[t] += v;
        __syncthreads();
    }
    if (i < N) excl[i] = sm[t] - d;
    if (t == 255) blocksum[blockIdx.x] = sm[255];
}

// ============ scatter (+inline scanB; block 0 persists base for agg) ============
__global__ __launch_bounds__(256) void scatter_kernel(
    const int* __restrict__ src, const int* __restrict__ dst,
    const int* __restrict__ rank, const int* __restrict__ excl,
    const int* __restrict__ blocksum, int* __restrict__ base,
    unsigned* __restrict__ usrc_sorted, int E, int nb) {
    __shared__ int sm[256];
    __shared__ int base_lds[256];
    int t = threadIdx.x;
    int d0 = (t < nb) ? blocksum[t] : 0;
    sm[t] = d0; __syncthreads();
    for (int off = 1; off < 256; off <<= 1) {
        int v = (t >= off) ? sm[t - off] : 0;
        __syncthreads();
        sm[t] += v;
        __syncthreads();
    }
    base_lds[t] = sm[t] - d0;
    if (blockIdx.x == 0) base[t] = sm[t] - d0;   // persist for agg
    __syncthreads();

    int e = blockIdx.x * 256 + t;
    if (e >= E) return;
    int d = dst[e];
    int p = excl[d] + base_lds[d >> 8] + rank[e];
    usrc_sorted[p] = (unsigned)src[e] << 8;
}

// ============ aggregation: fp32-score readlane broadcast, 4x unrolled; fused BN ============
__global__ __launch_bounds__(256) void agg_kernel(
    const unsigned char* __restrict__ Hh8, const unsigned char* __restrict__ Hr8,
    const unsigned short* __restrict__ Rres, const float* __restrict__ el,
    const float* __restrict__ er,
    const int* __restrict__ excl, const int* __restrict__ base,
    const unsigned* __restrict__ usrc_sorted,
    const float* __restrict__ conv_w, const float* __restrict__ conv_b,
    float* __restrict__ y, float* __restrict__ bnsum8, float* __restrict__ bnsq8,
    int N, int E)
{
    __shared__ float smem[256];
    __shared__ float smem2[256];
    int t = threadIdx.x;
    int wave = t >> 6, lane = t & 63;
    int v = blockIdx.x * 4 + wave;

    float yv = 0.f;
    if (v < N) {
        int b  = excl[v] + base[v >> 8];
        int e2 = (v + 1 < N) ? (excl[v + 1] + base[(v + 1) >> 8]) : E;
        int deg = e2 - b;

        float4 rv = *(const float4*)(er + (size_t)v * 4);
        const unsigned char* hbase = Hh8 + lane * 4;
        float a0 = 0.f, a1 = 0.f, a2 = 0.f, a3 = 0.f;
        float p0 = 0.f, p1 = 0.f, p2 = 0.f, p3 = 0.f;

        for (int i0 = 0; i0 < deg; i0 += 64) {
            int j = i0 + lane;
            unsigned ux = 0;
            float s0 = 0.f, s1 = 0.f, s2 = 0.f, s3 = 0.f;
            if (j < deg) {
                ux = usrc_sorted[b + j];
                float4 l = *(const float4*)(el + ((size_t)(ux >> 8)) * 4);   // L2-hot (800 KB)
                float x;
                x = l.x + rv.x; x = x > 0.f ? x : NEG_SLOPE * x; s0 = __expf(x);
                x = l.y + rv.y; x = x > 0.f ? x : NEG_SLOPE * x; s1 = __expf(x);
                x = l.z + rv.z; x = x > 0.f ? x : NEG_SLOPE * x; s2 = __expf(x);
                x = l.w + rv.w; x = x > 0.f ? x : NEG_SLOPE * x; s3 = __expf(x);
                p0 += s0; p1 += s1; p2 += s2; p3 += s3;
            }
            int cl = deg - i0; if (cl > 64) cl = 64;
            int jj = 0;
            for (; jj + 3 < cl; jj += 4) {
                unsigned u_[4], hv[4];
                float w0[4], w1[4], w2[4], w3[4];
#pragma unroll
                for (int k = 0; k < 4; ++k) {
                    u_[k] = (unsigned)__builtin_amdgcn_readlane((int)ux, jj + k);
                    w0[k] = u2f((unsigned)__builtin_amdgcn_readlane((int)f2u(s0), jj + k));
                    w1[k] = u2f((unsigned)__builtin_amdgcn_readlane((int)f2u(s1), jj + k));
                    w2[k] = u2f((unsigned)__builtin_amdgcn_readlane((int)f2u(s2), jj + k));
                    w3[k] = u2f((unsigned)__builtin_amdgcn_readlane((int)f2u(s3), jj + k));
                }
#pragma unroll
                for (int k = 0; k < 4; ++k)
                    hv[k] = *(const unsigned*)(hbase + u_[k]);
#pragma unroll
                for (int k = 0; k < 4; ++k) {
                    f32x2 lo = __builtin_amdgcn_cvt_pk_f32_fp8(hv[k], false);
                    f32x2 hi = __builtin_amdgcn_cvt_pk_f32_fp8(hv[k], true);
                    a0 += w0[k] * lo.x;
                    a1 += w1[k] * lo.y;
                    a2 += w2[k] * hi.x;
                    a3 += w3[k] * hi.y;
                }
            }
            for (; jj < cl; ++jj) {
                unsigned uA = (unsigned)__builtin_amdgcn_readlane((int)ux, jj);
                float w0 = u2f((unsigned)__builtin_amdgcn_readlane((int)f2u(s0), jj));
                float w1 = u2f((unsigned)__builtin_amdgcn_readlane((int)f2u(s1), jj));
                float w2 = u2f((unsigned)__builtin_amdgcn_readlane((int)f2u(s2), jj));
                float w3 = u2f((unsigned)__builtin_amdgcn_readlane((int)f2u(s3), jj));
                unsigned hvA = *(const unsigned*)(hbase + uA);
                f32x2 lo = __builtin_amdgcn_cvt_pk_f32_fp8(hvA, false);
                f32x2 hi = __builtin_amdgcn_cvt_pk_f32_fp8(hvA, true);
                a0 += w0 * lo.x;
                a1 += w1 * lo.y;
                a2 += w2 * hi.x;
                a3 += w3 * hi.y;
            }
        }
#pragma unroll
        for (int off = 1; off < 64; off <<= 1) {
            p0 += __shfl_xor(p0, off); p1 += __shfl_xor(p1, off);
            p2 += __shfl_xor(p2, off); p3 += __shfl_xor(p3, off);
        }
        float r0 = 1.f / (p0 + 1e-16f), r1 = 1.f / (p1 + 1e-16f);
        float r2 = 1.f / (p2 + 1e-16f), r3 = 1.f / (p3 + 1e-16f);

        unsigned hr = *(const unsigned*)(Hr8 + ((size_t)v << 8) + lane * 4);
        f32x2 rlo = __builtin_amdgcn_cvt_pk_f32_fp8(hr, false);
        f32x2 rhi = __builtin_amdgcn_cvt_pk_f32_fp8(hr, true);
        float resv = bf2f(Rres[(size_t)v * OUTD + lane]);
        yv = conv_b[0] + (resv > 0.f ? resv : 0.f);
        float tt;
        tt = a0 * r0 + rlo.x; tt = tt > 0.f ? tt : 0.f; yv += conv_w[0] * tt;
        tt = a1 * r1 + rlo.y; tt = tt > 0.f ? tt : 0.f; yv += conv_w[1] * tt;
        tt = a2 * r2 + rhi.x; tt = tt > 0.f ? tt : 0.f; yv += conv_w[2] * tt;
        tt = a3 * r3 + rhi.y; tt = tt > 0.f ? tt : 0.f; yv += conv_w[3] * tt;
        y[(size_t)v * OUTD + lane] = yv;
    }

    // ---- fused BN partials: per-block LDS reduce -> 8-way split atomics ----
    smem[t] = yv;
    smem2[t] = yv * yv;
    __syncthreads();
    if (t < 64) {
        float s = smem[t] + smem[t + 64] + smem[t + 128] + smem[t + 192];
        float q = smem2[t] + smem2[t + 64] + smem2[t + 128] + smem2[t + 192];
        int c = (blockIdx.x & 7) << 6;
        atomicAdd(bnsum8 + c + t, s);
        atomicAdd(bnsq8 + c + t, q);
    }
}

// ============ norm: fold 8-copy BN sums (per-block LDS) then normalize ============
__global__ __launch_bounds__(256) void norm_kernel(
    const float* __restrict__ y,
    const float* __restrict__ bnsum8, const float* __restrict__ bnsq8,
    const float* __restrict__ gamma, const float* __restrict__ beta,
    float* __restrict__ out, int total4, float invN) {
    __shared__ float scale[64], shift[64];
    int t = threadIdx.x;
    if (t < 64) {
        float s = 0.f, q = 0.f;
#pragma unroll
        for (int c = 0; c < 8; ++c) { s += bnsum8[c * 64 + t]; q += bnsq8[c * 64 + t]; }
        float mean = s * invN;
        float var = q * invN - mean * mean;
        float sc = gamma[t] * rsqrtf(var + BN_EPS);
        scale[t] = sc;
        shift[t] = beta[t] - mean * sc;
    }
    __syncthreads();
    int idx = blockIdx.x * blockDim.x + t;
    if (idx >= total4) return;
    float4 v = *(const float4*)(y + (size_t)idx * 4);
    int d = (idx * 4) & 63;
    float4 o;
    o.x = v.x * scale[d + 0] + shift[d + 0];
    o.y = v.y * scale[d + 1] + shift[d + 1];
    o.z = v.z * scale[d + 2] + shift[d + 2];
    o.w = v.w * scale[d + 3] + shift[d + 3];
    *(float4*)(out + (size_t)idx * 4) = o;
}

// ============ launch ============
extern "C" void kernel_launch(void* const* d_in, const int* in_sizes, int n_in,
                              void* d_out, int out_size, void* d_ws, size_t ws_size,
                              hipStream_t stream) {
    const float* node_feats = (const float*)d_in[0];
    const float* W_fc       = (const float*)d_in[1];
    const float* attn_l     = (const float*)d_in[2];
    const float* attn_r     = (const float*)d_in[3];
    const float* gat_res_w  = (const float*)d_in[4];
    const float* gat_bias   = (const float*)d_in[5];
    const float* conv_w     = (const float*)d_in[6];
    const float* conv_b     = (const float*)d_in[7];
    const float* res_w      = (const float*)d_in[8];
    const float* res_b      = (const float*)d_in[9];
    const float* bn_gamma   = (const float*)d_in[10];
    const float* bn_beta    = (const float*)d_in[11];
    const int*   src        = (const int*)d_in[12];
    const int*   dst        = (const int*)d_in[13];

    const int N = in_sizes[0] / IN_F;
    const int E = in_sizes[12];
    const int nb = (N + 255) / 256;
    const int T = (N + 15) / 16;
    const int Gblocks = (T + 3) / 4;

    char* ws = (char*)d_ws;
    size_t off = 0;
    auto alloc = [&](size_t bytes) -> void* {
        void* p = (void*)(ws + off);
        off += (bytes + 255) & ~(size_t)255;
        return p;
    };

    // --- zero zone ---
    int*   degree  = (int*)alloc((size_t)N * 4);
    float* bnsum8  = (float*)alloc(8 * 64 * 4);
    float* bnsq8   = (float*)alloc(8 * 64 * 4);
    size_t zero_bytes = off;
    // --- rest ---
    int*            rank        = (int*)alloc((size_t)E * 4);
    int*            excl        = (int*)alloc((size_t)N * 4);
    int*            blocksum    = (int*)alloc(256 * 4);
    int*            base        = (int*)alloc(256 * 4);
    unsigned*       usrc_sorted = (unsigned*)alloc((size_t)E * 4);
    unsigned short* Btg2        = (unsigned short*)alloc((size_t)10 * 16 * 512 * 2);
    unsigned char*  Hh8         = (unsigned char*)alloc((size_t)N * 256);
    unsigned char*  Hr8         = (unsigned char*)alloc((size_t)N * 256);
    unsigned short* Rres        = (unsigned short*)alloc((size_t)N * OUTD * 2);
    float*          el          = (float*)alloc((size_t)N * 4 * 4);
    float*          er          = (float*)alloc((size_t)N * 4 * 4);
    float*          y           = (float*)alloc((size_t)N * OUTD * 4);
    (void)ws_size; (void)n_in; (void)out_size;

    hipMemsetAsync(d_ws, 0, zero_bytes, stream);

    // 0. pack B weights
    k0_pack<<<289, 256, 0, stream>>>(W_fc, gat_res_w, res_w, attn_l, attn_r, Btg2);
    // 1. GEMM blocks first, hist blocks last (R10-proven)
    k1_gemm<<<Gblocks + HISTB, 256, 0, stream>>>(node_feats, Btg2, gat_bias, res_b,
                                                 dst, degree, rank, Hh8, Hr8, Rres,
                                                 el, er, N, E, Gblocks);
    // 2. scanA (chunk scans + chunk sums)
    scanA_kernel<<<nb, 256, 0, stream>>>(degree, excl, blocksum, N);
    // 3. scatter (+inline scanB; block 0 persists base)
    scatter_kernel<<<(E + 255) / 256, 256, 0, stream>>>(src, dst, rank, excl, blocksum,
                                                        base, usrc_sorted, E, nb);
    // 4. aggregation + scores + epilogue + fused BN partials
    agg_kernel<<<(N + 3) / 4, 256, 0, stream>>>(Hh8, Hr8, Rres, el, er, excl, base,
                                                usrc_sorted, conv_w, conv_b, y,
                                                bnsum8, bnsq8, N, E);
    // 5. norm (folds BN finalize)
    norm_kernel<<<(N * OUTD / 4 + 255) / 256, 256, 0, stream>>>(y, bnsum8, bnsq8,
                                                                bn_gamma, bn_beta, (float*)d_out,
                                                                N * OUTD / 4, 1.f / (float)N);
}